// Round 10
// baseline (2669.004 us; speedup 1.0000x reference)
//
#include <hip/hip_runtime.h>

#define HH 192
#define WW 384
#define CC 16
#define OH 184
#define OW 376
#define NTAP 25
#define TILE 64

// Kernel A: S[b][y][x] = sum_c volume[...]; first nW threads also transpose weights:
// w_t[tn][kk][c][j] = w_off[kk][c][4*tn+j]
__global__ void prep_kernel(const float* __restrict__ vol, float* __restrict__ S,
                            const float* __restrict__ w_off, float4* __restrict__ w_t,
                            int nS, int nW) {
    int idx = blockIdx.x * 256 + threadIdx.x;
    if (idx < nS) {
        const float4* p = reinterpret_cast<const float4*>(vol + (size_t)idx * CC);
        float4 a = p[0], b = p[1], c = p[2], d = p[3];
        S[idx] = ((a.x + a.y) + (a.z + a.w)) + ((b.x + b.y) + (b.z + b.w))
               + ((c.x + c.y) + (c.z + c.w)) + ((d.x + d.y) + (d.z + d.w));
    }
    if (idx < nW) {
        int kk = (idx >> 4) % 25;
        int tn = idx / (25 * 16);
        w_t[idx] = *reinterpret_cast<const float4*>(w_off + ((idx & 15) + kk * 16) * 100 + 4 * tn);
    }
}

// 16 FMAs: acc.{x,y,z,w} += dot(4-channel v, weight quads w0..w3)
#define DOT4Q(acc, v, w0, w1, w2, w3) do {                                   \
    acc.x = fmaf(v.x, w0.x, acc.x); acc.x = fmaf(v.y, w1.x, acc.x);          \
    acc.x = fmaf(v.z, w2.x, acc.x); acc.x = fmaf(v.w, w3.x, acc.x);          \
    acc.y = fmaf(v.x, w0.y, acc.y); acc.y = fmaf(v.y, w1.y, acc.y);          \
    acc.y = fmaf(v.z, w2.y, acc.y); acc.y = fmaf(v.w, w3.y, acc.y);          \
    acc.z = fmaf(v.x, w0.z, acc.z); acc.z = fmaf(v.y, w1.z, acc.z);          \
    acc.z = fmaf(v.z, w2.z, acc.z); acc.z = fmaf(v.w, w3.z, acc.z);          \
    acc.w = fmaf(v.x, w0.w, acc.w); acc.w = fmaf(v.y, w1.w, acc.w);          \
    acc.w = fmaf(v.z, w2.w, acc.w); acc.w = fmaf(v.w, w3.w, acc.w);          \
} while (0)

// X-macro over the 25 taps (literal indices -> everything compile-time)
#define FOR_TAPS(X) X(0) X(1) X(2) X(3) X(4) X(5) X(6) X(7) X(8) X(9) \
    X(10) X(11) X(12) X(13) X(14) X(15) X(16) X(17) X(18) X(19) \
    X(20) X(21) X(22) X(23) X(24)

// Fused dilated 5x5 offset conv + bilinear sampling.
// Block: 128 thr = 2 waves; wave wid computes ALL 25 taps for ONE output row
// (oy = oy0 + 2*wid) x 64 px. Accumulators are 25 NAMED float4s (acc0..acc24)
// -> guaranteed registers (round 9's acc[25] array stayed in scratch: VGPR=84,
// +38MB spill writes). Weight addresses have zero lane/wid dependence -> pure
// s_load, and every wave on the CU walks the SAME sequential 160KB weight
// stream -> scalar-cache temporal sharing. Per (r,kx): 4 ds_read_b128 feed
// 1600 FMAs/thread (LDS ratio ~0.08; s_load demand 2 B/wave-cycle).
__global__ __launch_bounds__(128, 2) void dconv_kernel(
    const float* __restrict__ vol, const float* __restrict__ w_t,
    const float* __restrict__ b_off, const float* __restrict__ S,
    float* __restrict__ out)
{
    __shared__ float4 lds[4][6][73];   // [ch-quad][row][col]  28,032 B

    const int tid  = threadIdx.x;
    const int lane = tid & 63;
    const int wid  = tid >> 6;          // 0..1 (which output row)
    const int z    = blockIdx.z;        // b*2+p
    const int p    = z & 1;
    const int b    = z >> 1;
    const int gy   = blockIdx.y;        // 0..45
    const int oy0  = p + 4 * gy;
    const int ox0  = blockIdx.x * TILE;

    // stage 6 rows: global row = oy0 + 2t (t=0..5), cols ox0..ox0+71 (clamped), 16 ch
    {
        const float* __restrict__ vb = vol + (size_t)((b * HH + oy0) * WW) * CC;
        for (int i = tid; i < 6 * 72 * 4; i += 128) {
            const int colr = i % 72;
            const int rem  = i / 72;
            const int t    = rem % 6;
            const int q    = rem / 6;
            int colg = ox0 + colr; if (colg > WW - 1) colg = WW - 1;
            lds[q][t][colr] = *reinterpret_cast<const float4*>(
                vb + (size_t)(2 * t * WW + colg) * CC + 4 * q);
        }
    }
    __syncthreads();

    const float4* __restrict__ w4 = reinterpret_cast<const float4*>(w_t);

    // 25 named accumulators, init with bias
#define DECL_ACC(i) float4 acc##i = *reinterpret_cast<const float4*>(b_off + 4 * (i));
    FOR_TAPS(DECL_ACC)
#undef DECL_ACC

    #pragma unroll 1
    for (int r = 0; r < 5; ++r) {
        #pragma unroll 1
        for (int kx = 0; kx < 5; ++kx) {
            const int cl = lane + 2 * kx;
            const int tr = wid + r;              // this wave's input tile row
            const float4 v0 = lds[0][tr][cl];
            const float4 v1 = lds[1][tr][cl];
            const float4 v2 = lds[2][tr][cl];
            const float4 v3 = lds[3][tr][cl];
            const int kk = r * 5 + kx;
#define TAP_STEP(i) {                                                          \
            const float4* __restrict__ W = w4 + (size_t)((i) * 25 + kk) * 16;  \
            float4 w0, w1, w2, w3;                                             \
            w0 = W[0];  w1 = W[1];  w2 = W[2];  w3 = W[3];                     \
            DOT4Q(acc##i, v0, w0, w1, w2, w3);                                 \
            w0 = W[4];  w1 = W[5];  w2 = W[6];  w3 = W[7];                     \
            DOT4Q(acc##i, v1, w0, w1, w2, w3);                                 \
            w0 = W[8];  w1 = W[9];  w2 = W[10]; w3 = W[11];                    \
            DOT4Q(acc##i, v2, w0, w1, w2, w3);                                 \
            w0 = W[12]; w1 = W[13]; w2 = W[14]; w3 = W[15];                    \
            DOT4Q(acc##i, v3, w0, w1, w2, w3); }
            FOR_TAPS(TAP_STEP)
#undef TAP_STEP
        }
    }

    // sampling epilogue: lane's pixel, this wave's row, 25 taps x 2 groups
    const int ox = ox0 + lane;
    if (ox < OW) {
        const int oy = oy0 + 2 * wid;
        const float byv = (float)(4 + oy);
        const float* __restrict__ Sb = S + b * HH * WW;
        const size_t ob0 = (size_t)(((b * 2 + 0) * OH + oy) * OW + ox) * NTAP;
        const size_t ob1 = (size_t)(((b * 2 + 1) * OH + oy) * OW + ox) * NTAP;
#define TAP_EPI(i) {                                                           \
        const float kv = (float)(2 * ((i) / 5) - 4);                           \
        const float ku = (float)(2 * ((i) % 5) - 4);                           \
        const float4 a = acc##i;                                               \
        _Pragma("unroll")                                                      \
        for (int g = 0; g < 2; ++g) {                                          \
            const float dy = g == 0 ? a.x : a.y;                               \
            const float dx = g == 0 ? a.z : a.w;                               \
            const float rx = kv + dy;                                          \
            const float ry = ku + dx;                                          \
            int x0 = (int)rx;                                                  \
            int x1 = x0 + 1;                                                   \
            int y0 = (int)ry;                                                  \
            int y1 = y0 + 1;                                                   \
            int x0c = min(max(x0, 0), WW - 1);                                 \
            int x1c = min(max(x1, 0), WW - 1);                                 \
            int y0c = min(max(y0, 0), HH - 1);                                 \
            int y1c = min(max(y1, 0), HH - 1);                                 \
            const float fx0 = (float)x0c, fx1 = (float)x1c;                    \
            const float fy0 = (float)y0c, fy1 = (float)y1c;                    \
            const float w0v = (fy1 - ry)  * (fx1 - rx);                        \
            const float w1v = (fy1 - byv) * (rx - fx0);                        \
            const float w2v = (ry - fy0)  * (fx1 - rx);                        \
            const float w3v = (ry - fy0)  * (rx - fx0);                        \
            const float s00 = Sb[y0c * WW + x0c];                              \
            const float s01 = Sb[y0c * WW + x1c];                              \
            const float s10 = Sb[y1c * WW + x0c];                              \
            const float s11 = Sb[y1c * WW + x1c];                              \
            out[(g == 0 ? ob0 : ob1) + (i)]                                    \
                = w0v * s00 + w1v * s01 + w2v * s10 + w3v * s11;               \
        } }
        FOR_TAPS(TAP_EPI)
#undef TAP_EPI
    }
}

extern "C" void kernel_launch(void* const* d_in, const int* in_sizes, int n_in,
                              void* d_out, int out_size, void* d_ws, size_t ws_size,
                              hipStream_t stream) {
    const float* vol   = (const float*)d_in[0];
    const float* w_off = (const float*)d_in[1];
    const float* b_off = (const float*)d_in[2];
    float* out = (float*)d_out;

    float* S   = (float*)d_ws;                                   // 576 KiB
    float* w_t = (float*)((char*)d_ws + 2 * HH * WW * 4);        // 160 KB

    const int nS = 2 * HH * WW;
    const int nW = NTAP * 25 * 16;
    prep_kernel<<<(nS + 255) / 256, 256, 0, stream>>>(vol, S, w_off, (float4*)w_t, nS, nW);

    dim3 grid((OW + TILE - 1) / TILE, 46, 4);   // 6 x 46 x 4 = 1104 blocks
    dconv_kernel<<<grid, 128, 0, stream>>>(vol, w_t, b_off, S, out);
}

// Round 11
// 246.149 us; speedup vs baseline: 10.8431x; 10.8431x over previous
//
#include <hip/hip_runtime.h>

#define HH 192
#define WW 384
#define CC 16
#define OH 184
#define OW 376
#define NTAP 25
#define TILE 64

// Kernel A: S[b][y][x] = sum_c volume[...]; first nW threads also transpose weights:
// w_t[tn][kk][c][j] = w_off[kk][c][4*tn+j]
__global__ void prep_kernel(const float* __restrict__ vol, float* __restrict__ S,
                            const float* __restrict__ w_off, float4* __restrict__ w_t,
                            int nS, int nW) {
    int idx = blockIdx.x * 256 + threadIdx.x;
    if (idx < nS) {
        const float4* p = reinterpret_cast<const float4*>(vol + (size_t)idx * CC);
        float4 a = p[0], b = p[1], c = p[2], d = p[3];
        S[idx] = ((a.x + a.y) + (a.z + a.w)) + ((b.x + b.y) + (b.z + b.w))
               + ((c.x + c.y) + (c.z + c.w)) + ((d.x + d.y) + (d.z + d.w));
    }
    if (idx < nW) {
        int kk = (idx >> 4) % 25;
        int tn = idx / (25 * 16);
        w_t[idx] = *reinterpret_cast<const float4*>(w_off + ((idx & 15) + kk * 16) * 100 + 4 * tn);
    }
}

// 16 FMAs: acc.{x,y,z,w} += dot(4-channel v, weight quads w0..w3)
#define DOT4Q(acc, v, w0, w1, w2, w3) do {                                   \
    acc.x = fmaf(v.x, w0.x, acc.x); acc.x = fmaf(v.y, w1.x, acc.x);          \
    acc.x = fmaf(v.z, w2.x, acc.x); acc.x = fmaf(v.w, w3.x, acc.x);          \
    acc.y = fmaf(v.x, w0.y, acc.y); acc.y = fmaf(v.y, w1.y, acc.y);          \
    acc.y = fmaf(v.z, w2.y, acc.y); acc.y = fmaf(v.w, w3.y, acc.y);          \
    acc.z = fmaf(v.x, w0.z, acc.z); acc.z = fmaf(v.y, w1.z, acc.z);          \
    acc.z = fmaf(v.z, w2.z, acc.z); acc.z = fmaf(v.w, w3.z, acc.z);          \
    acc.w = fmaf(v.x, w0.w, acc.w); acc.w = fmaf(v.y, w1.w, acc.w);          \
    acc.w = fmaf(v.z, w2.w, acc.w); acc.w = fmaf(v.w, w3.w, acc.w);          \
} while (0)

// X-macro over up to 13 taps; i is a literal, guarded by compile-time (i)<NT
#define FOR13(X) X(0) X(1) X(2) X(3) X(4) X(5) X(6) X(7) X(8) X(9) X(10) X(11) X(12)

// One wave's work: NT taps starting at TB (all compile-time), one output row.
// Accumulators: 13 named float4 = 52 floats -> compiler register-allocates
// (25-acc variants spilled at 100 floats in rounds 9/10: hard budget learned).
template<int NT, int TB>
__device__ __forceinline__ void conv_row(
    const float4 (*lds)[6][73], const float4* __restrict__ w4,
    const float* __restrict__ b_off, const float* __restrict__ S_,
    float* __restrict__ out, int lane, int wr, int oy, int ox0, int b)
{
#define DECL_ACC(i) float4 acc##i = (i) < NT                                    \
        ? *reinterpret_cast<const float4*>(b_off + 4 * (TB + (i)))              \
        : float4{0.f, 0.f, 0.f, 0.f};
    FOR13(DECL_ACC)
#undef DECL_ACC

    #pragma unroll 1
    for (int r = 0; r < 5; ++r) {
        #pragma unroll 1
        for (int kx = 0; kx < 5; ++kx) {
            const int cl = lane + 2 * kx;
            const int tr = wr + r;
            const float4 v0 = lds[0][tr][cl];
            const float4 v1 = lds[1][tr][cl];
            const float4 v2 = lds[2][tr][cl];
            const float4 v3 = lds[3][tr][cl];
            const int kk = r * 5 + kx;
#define TAP_STEP(i) if ((i) < NT) {                                             \
            const float4* __restrict__ W =                                      \
                w4 + (size_t)((TB + (i)) * 25 + kk) * 16;                       \
            float4 w0, w1, w2, w3;                                              \
            w0 = W[0];  w1 = W[1];  w2 = W[2];  w3 = W[3];                      \
            DOT4Q(acc##i, v0, w0, w1, w2, w3);                                  \
            w0 = W[4];  w1 = W[5];  w2 = W[6];  w3 = W[7];                      \
            DOT4Q(acc##i, v1, w0, w1, w2, w3);                                  \
            w0 = W[8];  w1 = W[9];  w2 = W[10]; w3 = W[11];                     \
            DOT4Q(acc##i, v2, w0, w1, w2, w3);                                  \
            w0 = W[12]; w1 = W[13]; w2 = W[14]; w3 = W[15];                     \
            DOT4Q(acc##i, v3, w0, w1, w2, w3); }
            FOR13(TAP_STEP)
#undef TAP_STEP
        }
    }

    // sampling epilogue
    const int ox = ox0 + lane;
    if (ox >= OW) return;
    const float byv = (float)(4 + oy);
    const size_t ob0 = (size_t)(((b * 2 + 0) * OH + oy) * OW + ox) * NTAP;
    const size_t ob1 = (size_t)(((b * 2 + 1) * OH + oy) * OW + ox) * NTAP;
#define TAP_EPI(i) if ((i) < NT) {                                             \
        const int tn = TB + (i);                                               \
        const float kv = (float)(2 * (tn / 5) - 4);                            \
        const float ku = (float)(2 * (tn % 5) - 4);                            \
        const float4 a = acc##i;                                               \
        _Pragma("unroll")                                                      \
        for (int g = 0; g < 2; ++g) {                                          \
            const float dy = g == 0 ? a.x : a.y;                               \
            const float dx = g == 0 ? a.z : a.w;                               \
            const float rx = kv + dy;   /* pairs with W axis (ref quirk) */    \
            const float ry = ku + dx;   /* pairs with H axis */                \
            int x0 = (int)rx;           /* trunc == astype(int32) */           \
            int x1 = x0 + 1;                                                   \
            int y0 = (int)ry;                                                  \
            int y1 = y0 + 1;                                                   \
            int x0c = min(max(x0, 0), WW - 1);                                 \
            int x1c = min(max(x1, 0), WW - 1);                                 \
            int y0c = min(max(y0, 0), HH - 1);                                 \
            int y1c = min(max(y1, 0), HH - 1);                                 \
            const float fx0 = (float)x0c, fx1 = (float)x1c;                    \
            const float fy0 = (float)y0c, fy1 = (float)y1c;                    \
            const float w0v = (fy1 - ry)  * (fx1 - rx);                        \
            const float w1v = (fy1 - byv) * (rx - fx0);                        \
            const float w2v = (ry - fy0)  * (fx1 - rx);                        \
            const float w3v = (ry - fy0)  * (rx - fx0);                        \
            const float s00 = S_[y0c * WW + x0c];                              \
            const float s01 = S_[y0c * WW + x1c];                              \
            const float s10 = S_[y1c * WW + x0c];                              \
            const float s11 = S_[y1c * WW + x1c];                              \
            out[(g == 0 ? ob0 : ob1) + tn]                                     \
                = w0v * s00 + w1v * s01 + w2v * s10 + w3v * s11;               \
        } }
    FOR13(TAP_EPI)
#undef TAP_EPI
}

// Fused dilated 5x5 offset conv + bilinear sampling.
// Block: 256 thr = 4 waves. Wave w: output row oy0 + 2*(w>>1); taps 0-12 (w even,
// NT=13) or 13-24 (w odd, NT=12) -- compile-time via template, wave-uniform branch.
// LDS ratio per (r,kx): 4 ds_read_b128 per ~208 FMAs/thread (0.37 of LDS peak vs
// round-8's 1.2 co-saturation). 2 weight streams/block (vs 5), all scalar loads.
__global__ __launch_bounds__(256) void dconv_kernel(
    const float* __restrict__ vol, const float* __restrict__ w_t,
    const float* __restrict__ b_off, const float* __restrict__ S,
    float* __restrict__ out)
{
    __shared__ float4 lds[4][6][73];   // [ch-quad][row][col]  28,032 B

    const int tid  = threadIdx.x;
    const int lane = tid & 63;
    const int wid  = tid >> 6;          // 0..3
    const int z    = blockIdx.z;        // b*2+p
    const int p    = z & 1;
    const int b    = z >> 1;
    const int gy   = blockIdx.y;        // 0..45
    const int oy0  = p + 4 * gy;
    const int ox0  = blockIdx.x * TILE;

    // stage 6 rows: global row = oy0 + 2t (t=0..5), cols ox0..ox0+71 (clamped), 16 ch
    {
        const float* __restrict__ vb = vol + (size_t)((b * HH + oy0) * WW) * CC;
        for (int i = tid; i < 6 * 72 * 4; i += 256) {
            const int colr = i % 72;
            const int rem  = i / 72;
            const int t    = rem % 6;
            const int q    = rem / 6;
            int colg = ox0 + colr; if (colg > WW - 1) colg = WW - 1;
            lds[q][t][colr] = *reinterpret_cast<const float4*>(
                vb + (size_t)(2 * t * WW + colg) * CC + 4 * q);
        }
    }
    __syncthreads();

    const float4* __restrict__ w4 = reinterpret_cast<const float4*>(w_t);
    const float* __restrict__ Sb  = S + b * HH * WW;
    const int wr = wid >> 1;                 // which of the 2 output rows
    const int oy = oy0 + 2 * wr;

    if ((wid & 1) == 0)
        conv_row<13, 0>(lds, w4, b_off, Sb, out, lane, wr, oy, ox0, b);
    else
        conv_row<12, 13>(lds, w4, b_off, Sb, out, lane, wr, oy, ox0, b);
}

extern "C" void kernel_launch(void* const* d_in, const int* in_sizes, int n_in,
                              void* d_out, int out_size, void* d_ws, size_t ws_size,
                              hipStream_t stream) {
    const float* vol   = (const float*)d_in[0];
    const float* w_off = (const float*)d_in[1];
    const float* b_off = (const float*)d_in[2];
    float* out = (float*)d_out;

    float* S   = (float*)d_ws;                                   // 576 KiB
    float* w_t = (float*)((char*)d_ws + 2 * HH * WW * 4);        // 160 KB

    const int nS = 2 * HH * WW;
    const int nW = NTAP * 25 * 16;
    prep_kernel<<<(nS + 255) / 256, 256, 0, stream>>>(vol, S, w_off, (float4*)w_t, nS, nW);

    dim3 grid((OW + TILE - 1) / TILE, 46, 4);   // 6 x 46 x 4 = 1104 blocks
    dconv_kernel<<<grid, 256, 0, stream>>>(vol, w_t, b_off, S, out);
}